// Round 2
// baseline (980.277 us; speedup 1.0000x reference)
//
#include <hip/hip_runtime.h>

// Problem constants (match reference setup_inputs)
#define NB 4096   // batch
#define TT 128    // seq len
#define EE 256    // embed dim
#define HH 64     // head dim

typedef __attribute__((ext_vector_type(8))) short bf16x8;
typedef __attribute__((ext_vector_type(4))) float f32x4;
typedef __attribute__((ext_vector_type(4))) unsigned short u16x4;

__device__ __forceinline__ unsigned short f2bf(float f) {
  union { float f; unsigned u; } c; c.f = f;
  return (unsigned short)((c.u + 0x7fffu + ((c.u >> 16) & 1u)) >> 16);
}

__device__ __forceinline__ bf16x8 cvt8(f32x4 a, f32x4 b) {
  bf16x8 r;
  r[0] = (short)f2bf(a[0]); r[1] = (short)f2bf(a[1]);
  r[2] = (short)f2bf(a[2]); r[3] = (short)f2bf(a[3]);
  r[4] = (short)f2bf(b[0]); r[5] = (short)f2bf(b[1]);
  r[6] = (short)f2bf(b[2]); r[7] = (short)f2bf(b[3]);
  return r;
}

// ---- XOR-swizzled LDS layouts (no padding; keeps ds_read_b128 conflict-free)
// Q/K: [t=128][h=64], 8-el blocks swizzled by t
__device__ __forceinline__ int qk_idx(int t, int h) {
  return t * 64 + ((((h >> 3) ^ t) & 7) << 3) + (h & 7);
}
// P: [t=128][c=128], swizzled by t
__device__ __forceinline__ int p_idx(int t, int c) {
  return t * 128 + ((((c >> 3) ^ t) & 15) << 3) + (c & 7);
}
// V^T: [h=64][t=128], swizzled by h
__device__ __forceinline__ int vt_idx(int h, int t) {
  return h * 128 + ((((t >> 3) ^ h) & 15) << 3) + (t & 7);
}

// wt[n][e] = W_{n/64}[e][n%64], bf16, B^T-row-contiguous for the MFMA B operand
__global__ void prep_w(const float* __restrict__ wq, const float* __restrict__ wk,
                       const float* __restrict__ wv, unsigned short* __restrict__ wt) {
  int n = blockIdx.x;    // 0..191
  int e = threadIdx.x;   // 0..255
  const float* w = (n < 64) ? wq : (n < 128) ? wk : wv;
  wt[n * EE + e] = f2bf(w[e * HH + (n & 63)]);
}

__global__ __launch_bounds__(256, 3)
void attn_fused(const float* __restrict__ x, const unsigned short* __restrict__ wt,
                float* __restrict__ out) {
  // 49,152 B total -> 3 blocks/CU.
  // sbuf[0..8191]     : Q [128][64]   (aliased by P cols 0..63 later)
  // sbuf[8192..16383] : K [128][64]   (aliased by P cols 64..127 later)
  // sbuf[16384..24575]: V^T [64][128]
  __shared__ __align__(16) unsigned short sbuf[24576];
  unsigned short* qbuf = sbuf;
  unsigned short* kbuf = sbuf + 8192;
  unsigned short* vbuf = sbuf + 16384;
  unsigned short* pbuf = sbuf;   // alias over Q+K, valid after post-S barrier

  const int b    = blockIdx.x;
  const int tid  = threadIdx.x;
  const int w    = tid >> 6;    // wave 0..3
  const int lane = tid & 63;
  const int quad = lane >> 4;   // 0..3
  const int l16  = lane & 15;
  const int m0   = 32 * w;      // this wave owns rows [m0, m0+32)

  const float* __restrict__ xb = x + (size_t)b * TT * EE;

  // ---------------- Phase 1: [Q|K|V] = x @ [Wq|Wk|Wv]  (M=128, N=192, K=256)
  // Prefetch ALL x A-fragments for this wave's two m-rows into registers:
  // 32 independent b128 loads -> deep MLP; converted to bf16 as they land.
  bf16x8 axf[8][2];   // [kc][mt] : 64 VGPRs
#pragma unroll
  for (int kc = 0; kc < 8; ++kc) {
#pragma unroll
    for (int mt = 0; mt < 2; ++mt) {
      const float* src = xb + (m0 + 16 * mt + l16) * EE + kc * 32 + quad * 8;
      f32x4 f0 = *(const f32x4*)src;
      f32x4 f1 = *(const f32x4*)(src + 4);
      axf[kc][mt] = cvt8(f0, f1);
    }
  }

  // Three passes (Q, K, V): only 8 accumulators live at a time.
#pragma unroll
  for (int pass = 0; pass < 3; ++pass) {
    f32x4 acc[4][2];
#pragma unroll
    for (int j = 0; j < 4; ++j)
#pragma unroll
      for (int mt = 0; mt < 2; ++mt)
        acc[j][mt] = (f32x4){0.f, 0.f, 0.f, 0.f};

#pragma unroll
    for (int kc = 0; kc < 8; ++kc) {
#pragma unroll
      for (int j = 0; j < 4; ++j) {
        int nt = pass * 4 + j;
        bf16x8 bfr = *(const bf16x8*)(wt + (nt * 16 + l16) * EE + kc * 32 + quad * 8);
        acc[j][0] = __builtin_amdgcn_mfma_f32_16x16x32_bf16(axf[kc][0], bfr, acc[j][0], 0, 0, 0);
        acc[j][1] = __builtin_amdgcn_mfma_f32_16x16x32_bf16(axf[kc][1], bfr, acc[j][1], 0, 0, 0);
      }
    }

    // Scatter this pass's result to LDS (bf16).
    // C-layout: row = rbase + reg, col = nt*16 + l16 (within the 64-wide matrix).
#pragma unroll
    for (int j = 0; j < 4; ++j) {
      int col = j * 16 + l16;            // 0..63 within Q/K/V
#pragma unroll
      for (int mt = 0; mt < 2; ++mt) {
        int rbase = m0 + 16 * mt + 4 * quad;
        if (pass == 0) {
#pragma unroll
          for (int r = 0; r < 4; ++r)
            qbuf[qk_idx(rbase + r, col)] = f2bf(acc[j][mt][r]);
        } else if (pass == 1) {
#pragma unroll
          for (int r = 0; r < 4; ++r)
            kbuf[qk_idx(rbase + r, col)] = f2bf(acc[j][mt][r]);
        } else {
          // V^T[h=col][t=rbase..rbase+3] : 4 consecutive t -> one 8B write
          u16x4 pk;
          pk[0] = f2bf(acc[j][mt][0]); pk[1] = f2bf(acc[j][mt][1]);
          pk[2] = f2bf(acc[j][mt][2]); pk[3] = f2bf(acc[j][mt][3]);
          *(u16x4*)(vbuf + vt_idx(col, rbase)) = pk;
        }
      }
    }
  }
  __syncthreads();

  // ---------------- Phase 2: S = Q K^T / 8, causal, softmax -> P (bf16, LDS)
  const int ntS = 2 * w + 2;   // wave w touches column tiles [0, ntS)
  f32x4 sacc[8][2];
#pragma unroll
  for (int nt = 0; nt < 8; ++nt)
#pragma unroll
    for (int mt = 0; mt < 2; ++mt)
      sacc[nt][mt] = (f32x4){0.f, 0.f, 0.f, 0.f};

#pragma unroll
  for (int kk = 0; kk < 2; ++kk) {
    bf16x8 aq[2];
    aq[0] = *(const bf16x8*)(qbuf + qk_idx(m0 + l16, kk * 32 + quad * 8));
    aq[1] = *(const bf16x8*)(qbuf + qk_idx(m0 + 16 + l16, kk * 32 + quad * 8));
#pragma unroll
    for (int nt = 0; nt < 8; ++nt) {
      if (nt < ntS) {   // wave-uniform
        bf16x8 bk = *(const bf16x8*)(kbuf + qk_idx(nt * 16 + l16, kk * 32 + quad * 8));
        sacc[nt][0] = __builtin_amdgcn_mfma_f32_16x16x32_bf16(aq[0], bk, sacc[nt][0], 0, 0, 0);
        sacc[nt][1] = __builtin_amdgcn_mfma_f32_16x16x32_bf16(aq[1], bk, sacc[nt][1], 0, 0, 0);
      }
    }
  }
  __syncthreads();  // all waves done reading Q/K -> region reusable as P

  const float scale = 0.125f;  // 1/sqrt(64)
#pragma unroll
  for (int mt = 0; mt < 2; ++mt) {
#pragma unroll
    for (int r = 0; r < 4; ++r) {
      int row = m0 + 16 * mt + 4 * quad + r;
      float mx = -3.0e38f;
#pragma unroll
      for (int nt = 0; nt < 8; ++nt) {
        if (nt < ntS) {
          int c = nt * 16 + l16;
          float s = (c <= row) ? sacc[nt][mt][r] * scale : -3.0e38f;
          sacc[nt][mt][r] = s;
          mx = fmaxf(mx, s);
        }
      }
#pragma unroll
      for (int off = 1; off < 16; off <<= 1) mx = fmaxf(mx, __shfl_xor(mx, off, 64));
      float sum = 0.f;
#pragma unroll
      for (int nt = 0; nt < 8; ++nt) {
        if (nt < ntS) {
          float e = __expf(sacc[nt][mt][r] - mx);
          sacc[nt][mt][r] = e;
          sum += e;
        }
      }
#pragma unroll
      for (int off = 1; off < 16; off <<= 1) sum += __shfl_xor(sum, off, 64);
      float inv = 1.0f / sum;
#pragma unroll
      for (int nt = 0; nt < 8; ++nt) {
        if (nt < ntS)
          pbuf[p_idx(row, nt * 16 + l16)] = f2bf(sacc[nt][mt][r] * inv);
      }
    }
  }
  // No barrier: wave w reads only its own P rows below; V^T synced after phase 1.

  // ---------------- Phase 3: out = P @ V   (M=128, N=64, K=128, causal-clipped)
  f32x4 oacc[4][2];
#pragma unroll
  for (int nt = 0; nt < 4; ++nt)
#pragma unroll
    for (int mt = 0; mt < 2; ++mt)
      oacc[nt][mt] = (f32x4){0.f, 0.f, 0.f, 0.f};

  for (int ks = 0; ks <= w; ++ks) {   // only K-tiles that can be nonzero
    bf16x8 ap[2];
    ap[0] = *(const bf16x8*)(pbuf + p_idx(m0 + l16, ks * 32 + quad * 8));
    ap[1] = *(const bf16x8*)(pbuf + p_idx(m0 + 16 + l16, ks * 32 + quad * 8));
#pragma unroll
    for (int nt = 0; nt < 4; ++nt) {
      bf16x8 bv = *(const bf16x8*)(vbuf + vt_idx(nt * 16 + l16, ks * 32 + quad * 8));
      oacc[nt][0] = __builtin_amdgcn_mfma_f32_16x16x32_bf16(ap[0], bv, oacc[nt][0], 0, 0, 0);
      oacc[nt][1] = __builtin_amdgcn_mfma_f32_16x16x32_bf16(ap[1], bv, oacc[nt][1], 0, 0, 0);
    }
  }

  float* __restrict__ ob = out + (size_t)b * TT * HH;
#pragma unroll
  for (int mt = 0; mt < 2; ++mt) {
#pragma unroll
    for (int r = 0; r < 4; ++r) {
      int row = m0 + 16 * mt + 4 * quad + r;
#pragma unroll
      for (int nt = 0; nt < 4; ++nt)
        ob[row * HH + nt * 16 + l16] = oacc[nt][mt][r];
    }
  }
}

extern "C" void kernel_launch(void* const* d_in, const int* in_sizes, int n_in,
                              void* d_out, int out_size, void* d_ws, size_t ws_size,
                              hipStream_t stream) {
  const float* x  = (const float*)d_in[0];
  const float* wq = (const float*)d_in[1];
  const float* wk = (const float*)d_in[2];
  const float* wv = (const float*)d_in[3];
  unsigned short* wt = (unsigned short*)d_ws;  // 192*256*2 = 98304 B
  float* outp = (float*)d_out;

  prep_w<<<dim3(192), dim3(256), 0, stream>>>(wq, wk, wv, wt);
  attn_fused<<<dim3(NB), dim3(256), 0, stream>>>(x, wt, outp);
}